// Round 14
// baseline (786.496 us; speedup 1.0000x reference)
//
#include <hip/hip_runtime.h>

// 4-level lifting wavelet, fully fused. R14: persistent blocks + cross-tile
// software pipeline.
//  - 2048 blocks (exactly 8/CU), each processes 8 (row,chunk=2048) tiles.
//  - LDS double buffer (2 x 2304 floats = 18.4 KB -> 8 blocks/CU = 32 waves).
//    stage(k+1) via global_load_lds is issued right after tile k's top
//    barrier -> lands during tile k's compute; per-wave vmcnt(0) at the next
//    tile top is then ~free. Blocks de-phase across the 8-tile loop (no
//    re-dispatch lockstep) -> smoother HBM demand.
//  - CHUNK=2048: all levels use M=9 with EXACT thread counts T=128/64/32/16
//    (M*T==NP), so lift_read needs no upper clamp. Exact-state warm-up (R10).
//  - R12's proven nt-store pattern (16B lane-contiguous = full-line coverage
//    per instruction; R13's 32B-stride nt stores caused +11% WRITE_SIZE).
#define BS    256
#define CHUNK 2048
#define HALO  256
#define NN    65536
#define TFL   2304   // floats per tile buffer
#define NT    8      // tiles per block

typedef float f4 __attribute__((ext_vector_type(4)));

__device__ __forceinline__ void ntst4(float* dst, const float* src) {
  __builtin_nontemporal_store(*(const f4*)src, (f4*)dst);
}

template<int M, int T, int NP>
__device__ __forceinline__ void lift_read(const float* __restrict__ A, int inOff,
                                          int t, float* __restrict__ in) {
  if (t >= T) return;
  const int p0 = M * t - 8;
#pragma unroll
  for (int i = 0; i < M + 8; ++i) {
    int p = p0 + i;
    p = p < 0 ? 0 : p;               // upper bound never hit: M*T == NP
    float2 v = *(const float2*)&A[inOff + 2 * p];
    in[2 * i] = v.x;
    in[2 * i + 1] = v.y;
  }
}

template<int M, int T, int NP>
__device__ __forceinline__ void lift_write(float* __restrict__ A, int avgOff,
                                           int detOff, int t,
                                           const float* __restrict__ in,
                                           const float* __restrict__ P6,
                                           const float* __restrict__ U6) {
  if (t >= T) return;
  const float P0 = P6[0], P1 = P6[1], P2 = P6[2], P3 = P6[3], P4 = P6[4], P5 = P6[5];
  const float U0 = U6[0], U1 = U6[1], U2 = U6[2], U3 = U6[3], U4 = U6[4], U5 = U6[5];
  const int p0 = M * t - 8;
  float dd[6], aa[4], ff[2];   // exact-state warm-up (values identical to recurrence)
#pragma unroll
  for (int k = 0; k < 6; ++k)
    dd[k] = in[2 * (k + 2) + 1] - (P0 * in[2 * (k + 2)] + P1 * in[2 * (k + 1)] + P2 * in[2 * k]);
#pragma unroll
  for (int k = 0; k < 4; ++k)
    aa[k] = in[2 * (k + 4)] + (U0 * dd[k + 2] + U1 * dd[k + 1] + U2 * dd[k]);
#pragma unroll
  for (int k = 0; k < 2; ++k)
    ff[k] = dd[k + 4] - (P3 * aa[k + 2] + P4 * aa[k + 1] + P5 * aa[k]);
  float e1 = in[14], e2 = in[12];
  float d1 = dd[5], d2 = dd[4], a1 = aa[3], a2 = aa[2], f1 = ff[1], f2 = ff[0];
#pragma unroll
  for (int i = 8; i < M + 8; ++i) {
    float e0 = in[2 * i], o0 = in[2 * i + 1];
    float d0 = o0 - (P0 * e0 + P1 * e1 + P2 * e2);
    float a0 = e0 + (U0 * d0 + U1 * d1 + U2 * d2);
    float f0 = d0 - (P3 * a0 + P4 * a1 + P5 * a2);
    float b0 = a0 + (U3 * f0 + U4 * f1 + U5 * f2);
    int p = p0 + i;               // = M*t + (i-8), in [0, NP)
    A[avgOff + p] = b0;
    A[detOff + p] = f0;
    e2 = e1; e1 = e0; d2 = d1; d1 = d0; a2 = a1; a1 = a0; f2 = f1; f1 = f0;
  }
}

__global__ __launch_bounds__(BS, 8)
void wavelet_fused_kernel(const float* __restrict__ x,
                          const float* __restrict__ Pc,
                          const float* __restrict__ Uc,
                          float* __restrict__ out) {
  __shared__ __align__(16) float A[2 * TFL];   // 18.4 KB

  const int tid  = threadIdx.x;
  const int wave = tid >> 6;
  const int lane = tid & 63;
  const int bid  = blockIdx.x;
  const int row  = bid >> 2;          // 0..511
  const int cx0  = (bid & 3) * NT;    // 0,8,16,24

  const float4* x4 = (const float4*)(x + (size_t)row * NN);
  const int mask4 = NN / 4 - 1;

  // ---- prologue: stage tile 0 into buffer 0 ----
  {
    const int base4 = ((cx0 * CHUNK - HALO) & (NN - 1)) >> 2;
    for (int s = wave; s < 9; s += 4) {
      const float4* g = &x4[(base4 + s * 64 + lane) & mask4];
      __builtin_amdgcn_global_load_lds(
          (const __attribute__((address_space(1))) void*)g,
          (__attribute__((address_space(3))) void*)&A[s * 256], 16, 0, 0);
    }
  }

#pragma unroll 1
  for (int k = 0; k < NT; ++k) {
    float* C = A + (k & 1) * TFL;
    const int S = (cx0 + k) * CHUNK;

    asm volatile("s_waitcnt vmcnt(0)" ::: "memory");
    __syncthreads();                   // (1) stage(k) landed block-wide

    // issue stage(k+1) into the other buffer (hidden under tile-k compute)
    if (k + 1 < NT) {
      float* D = A + ((k + 1) & 1) * TFL;
      const int base4 = (((cx0 + k + 1) * CHUNK - HALO) & (NN - 1)) >> 2;
      for (int s = wave; s < 9; s += 4) {
        const float4* g = &x4[(base4 + s * 64 + lane) & mask4];
        __builtin_amdgcn_global_load_lds(
            (const __attribute__((address_space(1))) void*)g,
            (__attribute__((address_space(3))) void*)&D[s * 256], 16, 0, 0);
      }
    }

    float* z0 = out + (size_t)row * 32768 + (S >> 1);
    float* z1 = out + 16777216 + (size_t)row * 16384 + (S >> 2);
    float* z2 = out + 25165824 + (size_t)row * 8192 + (S >> 3);
    float* z3 = out + 29360128 + (size_t)row * 4096 + (S >> 4);
    float* z4 = out + 31457280 + (size_t)row * 4096 + (S >> 4);

    // ---- L0: 1152 pairs [0,2304) -> avg [0,1152), det [1152,2304) ----
    {
      float in0[34];
      lift_read<9, 128, 1152>(C, 0, tid, in0);
      __syncthreads();                 // (2) WAR
      lift_write<9, 128, 1152>(C, 0, 1152, tid, in0, Pc, Uc);
    }
    __syncthreads();                   // (3)

    // ---- z0 store (tid>=128; avg pairs 128..1152 = C[128,1152)) ----
    // ---- || L1 read (tid<64) ----
    float in1[34];
    if (tid >= 128) {
      const int t = tid - 128;
      ntst4(z0 + 4 * t,         C + 128 + 4 * t);
      ntst4(z0 + 4 * (t + 128), C + 128 + 4 * (t + 128));
    } else {
      lift_read<9, 64, 576>(C, 1152, tid, in1);
    }
    __syncthreads();                   // (4)
    lift_write<9, 64, 576>(C, 1152, 1728, tid, in1, Pc + 6, Uc + 6);
    __syncthreads();                   // (5)

    // ---- z1 store (avg1 pairs 64..576 = C[1216,1728)) || L2 read ----
    float in2[34];
    if (tid >= 64 && tid < 192) {
      const int t = tid - 64;
      ntst4(z1 + 4 * t, C + 1216 + 4 * t);
    } else if (tid < 32) {
      lift_read<9, 32, 288>(C, 1728, tid, in2);
    }
    __syncthreads();                   // (6)
    lift_write<9, 32, 288>(C, 1728, 2016, tid, in2, Pc + 12, Uc + 12);
    __syncthreads();                   // (7)

    // ---- z2 store (avg2 pairs 32..288 = C[1760,2016)) || L3 read ----
    float in3[34];
    if (tid >= 32 && tid < 96) {
      const int t = tid - 32;
      ntst4(z2 + 4 * t, C + 1760 + 4 * t);
    } else if (tid < 16) {
      lift_read<9, 16, 144>(C, 2016, tid, in3);
    }
    __syncthreads();                   // (8)
    lift_write<9, 16, 144>(C, 2016, 2160, tid, in3, Pc + 18, Uc + 18);
    __syncthreads();                   // (9)

    // ---- z3 (avg3 pairs 16..144 = C[2032,2160)), z4 (det3 C[2176,2304)) ----
    if (tid >= 16 && tid < 48)       ntst4(z3 + 4 * (tid - 16), C + 2032 + 4 * (tid - 16));
    else if (tid >= 48 && tid < 80)  ntst4(z4 + 4 * (tid - 48), C + 2176 + 4 * (tid - 48));
  }
}

extern "C" void kernel_launch(void* const* d_in, const int* in_sizes, int n_in,
                              void* d_out, int out_size, void* d_ws, size_t ws_size,
                              hipStream_t stream) {
  const float* x  = (const float*)d_in[0];
  const float* Pc = (const float*)d_in[1];
  const float* Uc = (const float*)d_in[2];
  float* out = (float*)d_out;

  dim3 grid(2048, 1, 1);   // 8 blocks/CU exactly; 8 tiles each
  dim3 block(BS, 1, 1);
  wavelet_fused_kernel<<<grid, block, 0, stream>>>(x, Pc, Uc, out);
}

// Round 15
// 48.189 us; speedup vs baseline: 16.3212x; 16.3212x over previous
//
#include <hip/hip_runtime.h>

// 4-level lifting wavelet, fully fused. FINAL = R12 (best: 48.2 us).
//  - CHUNK=4096, BS=256, in-place LDS A[4352] = 17.4 KB -> 8 blocks/CU.
//  - global_load_lds staging of chunk + 256 circular halo.
//  - Exact-state warm-up (36 FMA) instead of 8-pair recurrence warm-up.
//  - Phase overlap: every z-store (tid>=128) runs concurrently with the next
//    level's register read (tid<128); in-place avg/det per level.
//  - Non-temporal lane-contiguous 16B output stores (full-line coverage;
//    NB: 32B-stride nt stores inflate WRITE_SIZE 11% — R13 lesson).
//  - NO outer tile loop / NO persistent blocks: R14 showed the k-loop's
//    register state spills catastrophically under launch_bounds(256,8).
#define BS    256
#define CHUNK 4096
#define HALO  256
#define NN    65536
#define LDSF  4352

typedef float f4 __attribute__((ext_vector_type(4)));

__device__ __forceinline__ void ntst4(float* dst, const float* src) {
  __builtin_nontemporal_store(*(const f4*)src, (f4*)dst);
}

template<int M, int T, int NP>
__device__ __forceinline__ void lift_read(const float* __restrict__ A, int inOff,
                                          int t, float* __restrict__ in) {
  if (t >= T) return;
  const int p0 = M * t - 8;
#pragma unroll
  for (int i = 0; i < M + 8; ++i) {
    int p = p0 + i;
    p = p < 0 ? 0 : (p >= NP ? NP - 1 : p);
    float2 v = *(const float2*)&A[inOff + 2 * p];
    in[2 * i] = v.x;
    in[2 * i + 1] = v.y;
  }
}

template<int M, int T, int NP>
__device__ __forceinline__ void lift_write(float* __restrict__ A, int avgOff,
                                           int detOff, int t,
                                           const float* __restrict__ in,
                                           const float* __restrict__ P6,
                                           const float* __restrict__ U6) {
  if (t >= T) return;
  const float P0 = P6[0], P1 = P6[1], P2 = P6[2], P3 = P6[3], P4 = P6[4], P5 = P6[5];
  const float U0 = U6[0], U1 = U6[1], U2 = U6[2], U3 = U6[3], U4 = U6[4], U5 = U6[5];
  const int p0 = M * t - 8;
  float dd[6], aa[4], ff[2];
#pragma unroll
  for (int k = 0; k < 6; ++k)
    dd[k] = in[2 * (k + 2) + 1] - (P0 * in[2 * (k + 2)] + P1 * in[2 * (k + 1)] + P2 * in[2 * k]);
#pragma unroll
  for (int k = 0; k < 4; ++k)
    aa[k] = in[2 * (k + 4)] + (U0 * dd[k + 2] + U1 * dd[k + 1] + U2 * dd[k]);
#pragma unroll
  for (int k = 0; k < 2; ++k)
    ff[k] = dd[k + 4] - (P3 * aa[k + 2] + P4 * aa[k + 1] + P5 * aa[k]);
  float e1 = in[14], e2 = in[12];
  float d1 = dd[5], d2 = dd[4], a1 = aa[3], a2 = aa[2], f1 = ff[1], f2 = ff[0];
#pragma unroll
  for (int i = 8; i < M + 8; ++i) {
    float e0 = in[2 * i], o0 = in[2 * i + 1];
    float d0 = o0 - (P0 * e0 + P1 * e1 + P2 * e2);
    float a0 = e0 + (U0 * d0 + U1 * d1 + U2 * d2);
    float f0 = d0 - (P3 * a0 + P4 * a1 + P5 * a2);
    float b0 = a0 + (U3 * f0 + U4 * f1 + U5 * f2);
    int p = p0 + i;
    if (p < NP) { A[avgOff + p] = b0; A[detOff + p] = f0; }
    e2 = e1; e1 = e0; d2 = d1; d1 = d0; a2 = a1; a1 = a0; f2 = f1; f1 = f0;
  }
}

__global__ __launch_bounds__(BS, 8)
void wavelet_fused_kernel(const float* __restrict__ x,
                          const float* __restrict__ Pc,
                          const float* __restrict__ Uc,
                          float* __restrict__ out) {
  __shared__ __align__(16) float A[LDSF];   // 17.4 KB

  const int tid  = threadIdx.x;
  const int wave = tid >> 6;
  const int lane = tid & 63;
  const int cx   = blockIdx.x;    // chunk 0..15
  const int row  = blockIdx.y;    // row 0..511
  const int S    = cx * CHUNK;

  // ---- stage CHUNK + HALO = 4352 floats (1088 float4 = 17 wave-slices) ----
  {
    const float4* x4 = (const float4*)(x + (size_t)row * NN);
    const int base4 = ((S - HALO) & (NN - 1)) >> 2;
    for (int s = wave; s < 17; s += 4) {
      const float4* g = &x4[(base4 + s * 64 + lane) & (NN / 4 - 1)];
      __builtin_amdgcn_global_load_lds(
          (const __attribute__((address_space(1))) void*)g,
          (__attribute__((address_space(3))) void*)&A[s * 256], 16, 0, 0);
    }
  }
  __syncthreads();   // (1)

  float* z0 = out + (size_t)row * 32768 + (S >> 1);
  float* z1 = out + 16777216 + (size_t)row * 16384 + (S >> 2);
  float* z2 = out + 25165824 + (size_t)row * 8192 + (S >> 3);
  float* z3 = out + 29360128 + (size_t)row * 4096 + (S >> 4);
  float* z4 = out + 31457280 + (size_t)row * 4096 + (S >> 4);

  // ---- L0: 2176 pairs in [0,4352) -> avg [0,2176), det [2176,4352) ----
  {
    float in0[34];
    lift_read<9, 242, 2176>(A, 0, tid, in0);
    __syncthreads();   // (2) WAR
    lift_write<9, 242, 2176>(A, 0, 2176, tid, in0, Pc, Uc);
  }
  __syncthreads();     // (3)

  // ---- z0 store (tid>=128; avg pairs 128..2176 = A[128..2176)) ----
  // ---- || L1 read (tid<128) ----
  float in1[34];
  if (tid >= 128) {
    const int t = tid - 128;
#pragma unroll
    for (int k = 0; k < 4; ++k)
      ntst4(z0 + 4 * (t + 128 * k), A + 128 + 4 * (t + 128 * k));
  } else {
    lift_read<9, 121, 1088>(A, 2176, tid, in1);
  }
  __syncthreads();     // (4)
  lift_write<9, 121, 1088>(A, 2176, 3264, tid, in1, Pc + 6, Uc + 6);
  __syncthreads();     // (5)

  // ---- z1 store (avg1 pairs 64..1088 = A[2240..3264)) || L2 read ----
  float in2[34];
  if (tid >= 128) {
    const int t = tid - 128;
#pragma unroll
    for (int k = 0; k < 2; ++k)
      ntst4(z1 + 4 * (t + 128 * k), A + 2240 + 4 * (t + 128 * k));
  } else {
    lift_read<9, 61, 544>(A, 3264, tid, in2);
  }
  __syncthreads();     // (6)
  lift_write<9, 61, 544>(A, 3264, 3808, tid, in2, Pc + 12, Uc + 12);
  __syncthreads();     // (7)

  // ---- z2 store (avg2 pairs 32..544 = A[3296..3808)) || L3 read ----
  float in3[26];
  if (tid >= 128) {
    const int t = tid - 128;
    ntst4(z2 + 4 * t, A + 3296 + 4 * t);
  } else {
    lift_read<5, 55, 272>(A, 3808, tid, in3);
  }
  __syncthreads();     // (8)
  lift_write<5, 55, 272>(A, 3808, 4080, tid, in3, Pc + 18, Uc + 18);
  __syncthreads();     // (9)

  // ---- z3 (avg3 pairs 16..272 = A[3824..4080)), z4 (det3 = A[4096..4352)) ----
  if (tid < 64)        ntst4(z3 + 4 * tid, A + 3824 + 4 * tid);
  else if (tid < 128)  ntst4(z4 + 4 * (tid - 64), A + 4096 + 4 * (tid - 64));
}

extern "C" void kernel_launch(void* const* d_in, const int* in_sizes, int n_in,
                              void* d_out, int out_size, void* d_ws, size_t ws_size,
                              hipStream_t stream) {
  const float* x  = (const float*)d_in[0];
  const float* Pc = (const float*)d_in[1];
  const float* Uc = (const float*)d_in[2];
  float* out = (float*)d_out;

  dim3 grid(NN / CHUNK, 512, 1);   // 16 x 512 = 8192 blocks
  dim3 block(BS, 1, 1);
  wavelet_fused_kernel<<<grid, block, 0, stream>>>(x, Pc, Uc, out);
}